// Round 10
// baseline (265.802 us; speedup 1.0000x reference)
//
#include <hip/hip_runtime.h>

// ---------------------------------------------------------------------------
// BCNet: v_=relu(v@Wv^T+bv); q_=relu(q@Wq^T+bq); out[b,h,v,q]=sum_k h[h,k]*v_*q_ + hbias[h]
// Round 10: round-9 cvt-fusion with the cvt_pkrtz return-type fix
// (__builtin_amdgcn_cvt_pkrtz returns __fp16x2; bit_cast to _Float16 lanes).
//  - GEMM-C/GEMM-D stage A directly from f32 (reg-stage + v_cvt_pkrtz +
//    swizzled ds_write), eliminating the v16/q16 HBM round trip (~201 MB).
//  - cvt kernel converts only Wv/Wq/h (29 MB, ~3us).
//  - bilinear unchanged (round-5 exact).
// ---------------------------------------------------------------------------

typedef _Float16 h8 __attribute__((ext_vector_type(8)));
typedef _Float16 h4 __attribute__((ext_vector_type(4)));
typedef __fp16 fp16x2 __attribute__((ext_vector_type(2)));
typedef float f32x4 __attribute__((ext_vector_type(4)));

#define B_   32
#define NV_  512
#define NQ_  128
#define VD_  2048
#define QD_  1024
#define HK_  1536
#define HO_  8

__device__ __forceinline__ void gload_lds16(const void* g, void* l) {
  __builtin_amdgcn_global_load_lds(
      (const __attribute__((address_space(1))) void*)g,
      (__attribute__((address_space(3))) void*)l, 16, 0, 0);
}

__device__ __forceinline__ h4 cvt4(float4 a) {
  struct P { fp16x2 lo, hi; } p;
  p.lo = __builtin_amdgcn_cvt_pkrtz(a.x, a.y);
  p.hi = __builtin_amdgcn_cvt_pkrtz(a.z, a.w);
  return __builtin_bit_cast(h4, p);
}

__device__ __forceinline__ h8 cvt8(float4 a, float4 b) {
  h4 lo = cvt4(a), hi = cvt4(b);
  h8 o;
  o[0] = lo[0]; o[1] = lo[1]; o[2] = lo[2]; o[3] = lo[3];
  o[4] = hi[0]; o[5] = hi[1]; o[6] = hi[2]; o[7] = hi[3];
  return o;
}

// ---------------------------------------------------------------------------
// f32 -> f16 for weights only: Wv (393216 u8), Wq (196608), h (1536);
// total 591360 8-elem units = 2310 * 256.
// ---------------------------------------------------------------------------
__global__ __launch_bounds__(256) void cvt_w(
    const float* __restrict__ Wv, const float* __restrict__ Wq,
    const float* __restrict__ hm,
    _Float16* __restrict__ Wv16, _Float16* __restrict__ Wq16,
    _Float16* __restrict__ h16) {
  int i = blockIdx.x * blockDim.x + threadIdx.x;
  const float* src;
  _Float16* dst;
  if (i < 393216)      { src = Wv; dst = Wv16; }
  else if (i < 589824) { src = Wq; dst = Wq16; i -= 393216; }
  else                 { src = hm; dst = h16;  i -= 589824; }
  const float4* p = (const float4*)src;
  float4 a = p[i * 2], b = p[i * 2 + 1];
  h8 o;
  o[0] = (_Float16)a.x; o[1] = (_Float16)a.y; o[2] = (_Float16)a.z; o[3] = (_Float16)a.w;
  o[4] = (_Float16)b.x; o[5] = (_Float16)b.y; o[6] = (_Float16)b.z; o[7] = (_Float16)b.w;
  ((h8*)dst)[i] = o;
}

// ---------------------------------------------------------------------------
// GEMM-C: out = relu(A32 @ Bw^T + bias); A32 f32 MxK, Bw f16 NxK.
// m97 structure: 128x128 tile, BK=64 (two [128][32] f16 kk-slabs), 4 waves,
// 64x64/wave, swizzle slot^=(row>>1)&3 (measured 0 conflicts), 3 blocks/CU.
// A-side: reg-staged from f32 + cvt_pkrtz + swizzled ds_write (cvt fusion).
// B-side: gload_lds from pre-converted f16 weights (pre-swizzled source).
// REMAP: chunked XCD remap (bijective; nwg % 8 == 0).
// ---------------------------------------------------------------------------
template <int KTOT, bool REMAP>
__global__ __launch_bounds__(256, 3) void gemm_c_relu(
    const float* __restrict__ A32, const _Float16* __restrict__ Bw,
    const float* __restrict__ bias, _Float16* __restrict__ out, int N) {
  __shared__ __align__(16) _Float16 As[2][128 * 32];
  __shared__ __align__(16) _Float16 Bs[2][128 * 32];

  const int t = threadIdx.x;
  const int lane = t & 63;
  const int wave = t >> 6;
  const int wm = wave >> 1, wn = wave & 1;

  int bcol, brow;
  if (REMAP) {
    const int nwg = gridDim.x * gridDim.y;
    const int j = blockIdx.y * gridDim.x + blockIdx.x;
    const int l = (j & 7) * (nwg >> 3) + (j >> 3);
    bcol = (l % gridDim.x) * 128;
    brow = (l / gridDim.x) * 128;
  } else {
    bcol = blockIdx.x * 128;
    brow = blockIdx.y * 128;
  }

  // B staging (f16): thread t -> row t>>2, 16B slot t&3, pre-swizzled source.
  const int scol = ((t & 3) ^ ((t >> 3) & 3)) * 8;
  const _Float16* Bb = Bw + (size_t)(bcol + (t >> 2)) * KTOT + scol;

  // A staging (f32 reg): thread t -> row t>>1 (0..127), slot-pair t&1.
  const int arow = t >> 1;
  const int ah = (t & 1) * 2;
  const float* Ab = A32 + (size_t)(brow + arow) * KTOT;
  const int aswz = (arow >> 1) & 3;

  f32x4 acc[4][4] = {};

  for (int kt = 0; kt < KTOT / 64; ++kt) {
    __syncthreads();  // previous tile's readers done
#pragma unroll
    for (int kk = 0; kk < 2; ++kk) {
      gload_lds16(Bb + kt * 64 + kk * 32, &Bs[kk][t * 8]);
      gload_lds16(Bb + (size_t)64 * KTOT + kt * 64 + kk * 32, &Bs[kk][2048 + t * 8]);
    }
    // A: 8 f32x4 loads issued together, then cvt+swizzled writes
    float4 f[8];
#pragma unroll
    for (int kk = 0; kk < 2; ++kk)
#pragma unroll
      for (int si = 0; si < 2; ++si) {
        const float* p = Ab + kt * 64 + kk * 32 + (ah + si) * 8;
        f[(kk * 2 + si) * 2] = *(const float4*)p;
        f[(kk * 2 + si) * 2 + 1] = *(const float4*)(p + 4);
      }
#pragma unroll
    for (int kk = 0; kk < 2; ++kk)
#pragma unroll
      for (int si = 0; si < 2; ++si) {
        const int phys = (ah + si) ^ aswz;
        *(h8*)&As[kk][arow * 32 + phys * 8] =
            cvt8(f[(kk * 2 + si) * 2], f[(kk * 2 + si) * 2 + 1]);
      }
    asm volatile("s_waitcnt vmcnt(0)" ::: "memory");
    __syncthreads();
#pragma unroll
    for (int kk = 0; kk < 2; ++kk) {
      h8 af[4], bf[4];
#pragma unroll
      for (int m = 0; m < 4; ++m) {
        const int row = wm * 64 + m * 16 + (lane & 15);
        af[m] = *(const h8*)&As[kk][row * 32 + ((lane >> 4) ^ ((row >> 1) & 3)) * 8];
      }
#pragma unroll
      for (int n = 0; n < 4; ++n) {
        const int row = wn * 64 + n * 16 + (lane & 15);
        bf[n] = *(const h8*)&Bs[kk][row * 32 + ((lane >> 4) ^ ((row >> 1) & 3)) * 8];
      }
#pragma unroll
      for (int m = 0; m < 4; ++m)
#pragma unroll
        for (int n = 0; n < 4; ++n)
          acc[m][n] = __builtin_amdgcn_mfma_f32_16x16x32_f16(af[m], bf[n], acc[m][n], 0, 0, 0);
    }
  }

#pragma unroll
  for (int m = 0; m < 4; ++m)
#pragma unroll
    for (int n = 0; n < 4; ++n) {
      const int col = bcol + wn * 64 + n * 16 + (lane & 15);
      const float bb = bias[col];
#pragma unroll
      for (int r = 0; r < 4; ++r) {
        const int row = brow + wm * 64 + m * 16 + (lane >> 4) * 4 + r;
        float val = acc[m][n][r] + bb;
        out[(size_t)row * N + col] = (_Float16)(val > 0.f ? val : 0.f);
      }
    }
}

// ---------------------------------------------------------------------------
// GEMM-D: BM=64 variant with the same f32-A cvt fusion. 64x128 tile, 4 waves,
// per-wave 32x64. Grid (12, M/64) = 768 blocks = all-resident at 3/CU.
// ---------------------------------------------------------------------------
template <int KTOT>
__global__ __launch_bounds__(256, 3) void gemm_d64_relu(
    const float* __restrict__ A32, const _Float16* __restrict__ Bw,
    const float* __restrict__ bias, _Float16* __restrict__ out, int N) {
  __shared__ __align__(16) _Float16 As[2][64 * 32];
  __shared__ __align__(16) _Float16 Bs[2][128 * 32];

  const int t = threadIdx.x;
  const int lane = t & 63;
  const int wave = t >> 6;
  const int wm = wave >> 1, wn = wave & 1;
  const int bcol = blockIdx.x * 128;
  const int brow = blockIdx.y * 64;

  const int scol = ((t & 3) ^ ((t >> 3) & 3)) * 8;
  const _Float16* Bb = Bw + (size_t)(bcol + (t >> 2)) * KTOT + scol;

  // A staging (f32 reg): thread t -> row t>>2 (0..63), slot t&3 (one per kk).
  const int arow = t >> 2;
  const int as = t & 3;
  const float* Ab = A32 + (size_t)(brow + arow) * KTOT;
  const int aphys = as ^ ((arow >> 1) & 3);

  f32x4 acc[2][4] = {};

  for (int kt = 0; kt < KTOT / 64; ++kt) {
    __syncthreads();
#pragma unroll
    for (int kk = 0; kk < 2; ++kk) {
      gload_lds16(Bb + kt * 64 + kk * 32, &Bs[kk][t * 8]);
      gload_lds16(Bb + (size_t)64 * KTOT + kt * 64 + kk * 32, &Bs[kk][2048 + t * 8]);
    }
    float4 f[4];
#pragma unroll
    for (int kk = 0; kk < 2; ++kk) {
      const float* p = Ab + kt * 64 + kk * 32 + as * 8;
      f[kk * 2] = *(const float4*)p;
      f[kk * 2 + 1] = *(const float4*)(p + 4);
    }
#pragma unroll
    for (int kk = 0; kk < 2; ++kk)
      *(h8*)&As[kk][arow * 32 + aphys * 8] = cvt8(f[kk * 2], f[kk * 2 + 1]);
    asm volatile("s_waitcnt vmcnt(0)" ::: "memory");
    __syncthreads();
#pragma unroll
    for (int kk = 0; kk < 2; ++kk) {
      h8 af[2], bf[4];
#pragma unroll
      for (int m = 0; m < 2; ++m) {
        const int row = wm * 32 + m * 16 + (lane & 15);
        af[m] = *(const h8*)&As[kk][row * 32 + ((lane >> 4) ^ ((row >> 1) & 3)) * 8];
      }
#pragma unroll
      for (int n = 0; n < 4; ++n) {
        const int row = wn * 64 + n * 16 + (lane & 15);
        bf[n] = *(const h8*)&Bs[kk][row * 32 + ((lane >> 4) ^ ((row >> 1) & 3)) * 8];
      }
#pragma unroll
      for (int m = 0; m < 2; ++m)
#pragma unroll
        for (int n = 0; n < 4; ++n)
          acc[m][n] = __builtin_amdgcn_mfma_f32_16x16x32_f16(af[m], bf[n], acc[m][n], 0, 0, 0);
    }
  }

#pragma unroll
  for (int m = 0; m < 2; ++m)
#pragma unroll
    for (int n = 0; n < 4; ++n) {
      const int col = bcol + wn * 64 + n * 16 + (lane & 15);
      const float bb = bias[col];
#pragma unroll
      for (int r = 0; r < 4; ++r) {
        const int row = brow + wm * 32 + m * 16 + (lane >> 4) * 4 + r;
        float val = acc[m][n][r] + bb;
        out[(size_t)row * N + col] = (_Float16)(val > 0.f ? val : 0.f);
      }
    }
}

// ---------------------------------------------------------------------------
// Bilinear (round-5 exact): out[b,h,v,q] = sum_k vh*(h16*qh) + hbias[h]
// ---------------------------------------------------------------------------
__global__ __launch_bounds__(256, 3) void bilinear_m97_f16(
    const _Float16* __restrict__ vh, const _Float16* __restrict__ qh,
    const _Float16* __restrict__ h16, const float* __restrict__ hbias,
    float* __restrict__ out) {
  __shared__ __align__(16) _Float16 As[2][128 * 32];
  __shared__ __align__(16) _Float16 Bs[2][128 * 32];
  __shared__ __align__(16) _Float16 hl[HK_];

  const int t = threadIdx.x;
  const int lane = t & 63;
  const int wave = t >> 6;
  const int wm = wave >> 1, wn = wave & 1;
  const int mt = blockIdx.x;
  const int bh = blockIdx.y;
  const int b = bh >> 3, h = bh & 7;

  const int scol = ((t & 3) ^ ((t >> 3) & 3)) * 8;
  const _Float16* Ab = vh + ((size_t)b * NV_ + mt * 128 + (t >> 2)) * HK_ + scol;
  const _Float16* Qb = qh + (size_t)b * NQ_ * HK_;

  for (int i = t; i < HK_ / 8; i += 256)
    *(h8*)&hl[i * 8] = *(const h8*)&h16[(size_t)h * HK_ + i * 8];

  const int qrow = t >> 2;
  const int qs = t & 3;

  f32x4 acc[4][4] = {};

  for (int kt = 0; kt < HK_ / 64; ++kt) {
    __syncthreads();
#pragma unroll
    for (int kk = 0; kk < 2; ++kk) {
      gload_lds16(Ab + kt * 64 + kk * 32, &As[kk][t * 8]);
      gload_lds16(Ab + (size_t)64 * HK_ + kt * 64 + kk * 32, &As[kk][2048 + t * 8]);
    }
#pragma unroll
    for (int u = 0; u < 2; ++u) {
      const int row = u * 64 + qrow;
#pragma unroll
      for (int kk = 0; kk < 2; ++kk) {
        const int col = kt * 64 + kk * 32 + qs * 8;
        h8 qv = *(const h8*)&Qb[(size_t)row * HK_ + col];
        h8 hv = *(const h8*)&hl[col];
        *(h8*)&Bs[kk][row * 32 + (qs ^ ((row >> 1) & 3)) * 8] = qv * hv;
      }
    }
    asm volatile("s_waitcnt vmcnt(0)" ::: "memory");
    __syncthreads();
#pragma unroll
    for (int kk = 0; kk < 2; ++kk) {
      h8 af[4], bf[4];
#pragma unroll
      for (int m = 0; m < 4; ++m) {
        const int row = wm * 64 + m * 16 + (lane & 15);
        af[m] = *(const h8*)&As[kk][row * 32 + ((lane >> 4) ^ ((row >> 1) & 3)) * 8];
      }
#pragma unroll
      for (int n = 0; n < 4; ++n) {
        const int row = wn * 64 + n * 16 + (lane & 15);
        bf[n] = *(const h8*)&Bs[kk][row * 32 + ((lane >> 4) ^ ((row >> 1) & 3)) * 8];
      }
#pragma unroll
      for (int m = 0; m < 4; ++m)
#pragma unroll
        for (int n = 0; n < 4; ++n)
          acc[m][n] = __builtin_amdgcn_mfma_f32_16x16x32_f16(af[m], bf[n], acc[m][n], 0, 0, 0);
    }
  }

  const float bb = hbias[h];
  float* O = out + ((size_t)bh * NV_ + (size_t)mt * 128) * NQ_;
#pragma unroll
  for (int m = 0; m < 4; ++m)
#pragma unroll
    for (int n = 0; n < 4; ++n)
#pragma unroll
      for (int r = 0; r < 4; ++r) {
        const int row = wm * 64 + m * 16 + (lane >> 4) * 4 + r;
        const int col = wn * 64 + n * 16 + (lane & 15);
        O[(size_t)row * NQ_ + col] = acc[m][n][r] + bb;
      }
}

// ---------------------------------------------------------------------------
// Workspace layout (bytes; v16/q16 slots now unused but offsets kept):
// Wv16@75497472 (6,291,456) Wq16@81788928 (3,145,728) vh@84934656 (50,331,648)
// qh@135266304 (12,582,912) h16@147849216 (24,576) total 147,873,792
// ---------------------------------------------------------------------------
extern "C" void kernel_launch(void* const* d_in, const int* in_sizes, int n_in,
                              void* d_out, int out_size, void* d_ws,
                              size_t ws_size, hipStream_t stream) {
  const float* v = (const float*)d_in[0];
  const float* q = (const float*)d_in[1];
  const float* Wv = (const float*)d_in[2];
  const float* bv = (const float*)d_in[3];
  const float* Wq = (const float*)d_in[4];
  const float* bq = (const float*)d_in[5];
  const float* hmat = (const float*)d_in[6];
  const float* hbias = (const float*)d_in[7];

  if (ws_size < 147873792u) return;

  char* ws = (char*)d_ws;
  _Float16* Wv16 = (_Float16*)(ws + 75497472);
  _Float16* Wq16 = (_Float16*)(ws + 81788928);
  _Float16* vh = (_Float16*)(ws + 84934656);
  _Float16* qh = (_Float16*)(ws + 135266304);
  _Float16* h16 = (_Float16*)(ws + 147849216);

  // weights + h only: 591360 units = 2310 * 256
  cvt_w<<<dim3(2310), 256, 0, stream>>>(Wv, Wq, hmat, Wv16, Wq16, h16);

  // v_ = relu(v @ Wv^T + bv): f32 A fused cvt; grid (12,128), XCD remap
  gemm_c_relu<VD_, true><<<dim3(HK_ / 128, 16384 / 128), 256, 0, stream>>>(
      v, Wv16, bv, vh, HK_);
  // q_ = relu(q @ Wq^T + bq): f32 A fused cvt; grid (12,64) = 768 all-resident
  gemm_d64_relu<QD_><<<dim3(HK_ / 128, 4096 / 64), 256, 0, stream>>>(
      q, Wq16, bq, qh, HK_);

  // logits: grid (4, 256) = 1024 blocks (round-5 exact)
  bilinear_m97_f16<<<dim3(NV_ / 128, B_ * HO_), 256, 0, stream>>>(
      vh, qh, h16, hbias, (float*)d_out);
}

// Round 11
// 236.345 us; speedup vs baseline: 1.1246x; 1.1246x over previous
//
#include <hip/hip_runtime.h>

// ---------------------------------------------------------------------------
// BCNet: v_=relu(v@Wv^T+bv); q_=relu(q@Wq^T+bq); out[b,h,v,q]=sum_k h[h,k]*v_*q_ + hbias[h]
// Round 11: exact revert to round 8 (best measured: 237.5us).
//  - cvt_all: fused f32->f16 for all inputs (HBM-floor, ~37.5us)
//  - GEMM-C: m97 128x128 / BK64 / 4 waves / 3 blocks/CU, conflict-free swizzle
//    slot^=(row>>1)&3, chunked XCD remap (848 TF = 93% of structure ceiling)
//  - GEMM-D: BM=64 variant, grid 768 = all-resident
//  - bilinear: m97 structure, fused h-scale in B staging
// Round-10's cvt fusion into GEMM (reg-staged f32 A) measured -70%: reverted.
// ---------------------------------------------------------------------------

typedef _Float16 h8 __attribute__((ext_vector_type(8)));
typedef float f32x4 __attribute__((ext_vector_type(4)));

#define B_   32
#define NV_  512
#define NQ_  128
#define VD_  2048
#define QD_  1024
#define HK_  1536
#define HO_  8

__device__ __forceinline__ void gload_lds16(const void* g, void* l) {
  __builtin_amdgcn_global_load_lds(
      (const __attribute__((address_space(1))) void*)g,
      (__attribute__((address_space(3))) void*)l, 16, 0, 0);
}

// ---------------------------------------------------------------------------
// Fused f32 -> f16 conversion for all 5 inputs, 8 elems/thread, one launch.
// Unit boundaries (8-elem units): v 4194304 | q 524288 | Wv 393216 |
// Wq 196608 | h 1536 => total 5309952 = 20742 * 256.
// ---------------------------------------------------------------------------
__global__ __launch_bounds__(256) void cvt_all(
    const float* __restrict__ v, const float* __restrict__ q,
    const float* __restrict__ Wv, const float* __restrict__ Wq,
    const float* __restrict__ hm,
    _Float16* __restrict__ v16, _Float16* __restrict__ q16,
    _Float16* __restrict__ Wv16, _Float16* __restrict__ Wq16,
    _Float16* __restrict__ h16) {
  int i = blockIdx.x * blockDim.x + threadIdx.x;
  const float* src;
  _Float16* dst;
  if (i < 4194304)      { src = v;  dst = v16; }
  else if (i < 4718592) { src = q;  dst = q16;  i -= 4194304; }
  else if (i < 5111808) { src = Wv; dst = Wv16; i -= 4718592; }
  else if (i < 5308416) { src = Wq; dst = Wq16; i -= 5111808; }
  else                  { src = hm; dst = h16;  i -= 5308416; }
  const float4* p = (const float4*)src;
  float4 a = p[i * 2], b = p[i * 2 + 1];
  h8 o;
  o[0] = (_Float16)a.x; o[1] = (_Float16)a.y; o[2] = (_Float16)a.z; o[3] = (_Float16)a.w;
  o[4] = (_Float16)b.x; o[5] = (_Float16)b.y; o[6] = (_Float16)b.z; o[7] = (_Float16)b.w;
  ((h8*)dst)[i] = o;
}

// ---------------------------------------------------------------------------
// m97 GEMM: out = relu(A @ Bw^T + bias). A: MxK, Bw: NxK (K-major).
// 128x128 tile, BK=64 as two [128][32] kk-slabs, 4 waves (2x2), 64x64/wave.
// Swizzle slot^=(row>>1)&3: measured 0 bank conflicts. 32 KB LDS, 3 blocks/CU.
// REMAP: chunked XCD remap (bijective; nwg % 8 == 0 for all launches here).
// ---------------------------------------------------------------------------
template <int KTOT, bool REMAP>
__global__ __launch_bounds__(256, 3) void gemm_m97_relu_f16(
    const _Float16* __restrict__ A, const _Float16* __restrict__ Bw,
    const float* __restrict__ bias, _Float16* __restrict__ out, int N) {
  __shared__ __align__(16) _Float16 As[2][128 * 32];
  __shared__ __align__(16) _Float16 Bs[2][128 * 32];

  const int t = threadIdx.x;
  const int lane = t & 63;
  const int wave = t >> 6;
  const int wm = wave >> 1, wn = wave & 1;

  int bcol, brow;
  if (REMAP) {
    const int nwg = gridDim.x * gridDim.y;
    const int j = blockIdx.y * gridDim.x + blockIdx.x;
    const int l = (j & 7) * (nwg >> 3) + (j >> 3);
    bcol = (l % gridDim.x) * 128;
    brow = (l / gridDim.x) * 128;
  } else {
    bcol = blockIdx.x * 128;
    brow = blockIdx.y * 128;
  }

  // staging: thread t -> row t>>2 (0..63), 16B slot t&3; LDS dest linear,
  // global source column pre-swizzled by the involution slot^=(row>>1)&3.
  const int scol = ((t & 3) ^ ((t >> 3) & 3)) * 8;
  const _Float16* Ab = A + (size_t)(brow + (t >> 2)) * KTOT + scol;
  const _Float16* Bb = Bw + (size_t)(bcol + (t >> 2)) * KTOT + scol;

  f32x4 acc[4][4] = {};

  for (int kt = 0; kt < KTOT / 64; ++kt) {
    __syncthreads();
#pragma unroll
    for (int kk = 0; kk < 2; ++kk) {
      gload_lds16(Ab + kt * 64 + kk * 32, &As[kk][t * 8]);
      gload_lds16(Ab + (size_t)64 * KTOT + kt * 64 + kk * 32, &As[kk][2048 + t * 8]);
      gload_lds16(Bb + kt * 64 + kk * 32, &Bs[kk][t * 8]);
      gload_lds16(Bb + (size_t)64 * KTOT + kt * 64 + kk * 32, &Bs[kk][2048 + t * 8]);
    }
    asm volatile("s_waitcnt vmcnt(0)" ::: "memory");
    __syncthreads();
#pragma unroll
    for (int kk = 0; kk < 2; ++kk) {
      h8 af[4], bf[4];
#pragma unroll
      for (int m = 0; m < 4; ++m) {
        const int row = wm * 64 + m * 16 + (lane & 15);
        af[m] = *(const h8*)&As[kk][row * 32 + ((lane >> 4) ^ ((row >> 1) & 3)) * 8];
      }
#pragma unroll
      for (int n = 0; n < 4; ++n) {
        const int row = wn * 64 + n * 16 + (lane & 15);
        bf[n] = *(const h8*)&Bs[kk][row * 32 + ((lane >> 4) ^ ((row >> 1) & 3)) * 8];
      }
#pragma unroll
      for (int m = 0; m < 4; ++m)
#pragma unroll
        for (int n = 0; n < 4; ++n)
          acc[m][n] = __builtin_amdgcn_mfma_f32_16x16x32_f16(af[m], bf[n], acc[m][n], 0, 0, 0);
    }
  }

#pragma unroll
  for (int m = 0; m < 4; ++m)
#pragma unroll
    for (int n = 0; n < 4; ++n) {
      const int col = bcol + wn * 64 + n * 16 + (lane & 15);
      const float bb = bias[col];
#pragma unroll
      for (int r = 0; r < 4; ++r) {
        const int row = brow + wm * 64 + m * 16 + (lane >> 4) * 4 + r;
        float val = acc[m][n][r] + bb;
        out[(size_t)row * N + col] = (_Float16)(val > 0.f ? val : 0.f);
      }
    }
}

// ---------------------------------------------------------------------------
// BM=64 m97 variant for the small q_ GEMM: 64x128 tile, 4 waves (2x2),
// per-wave 32x64. LDS 24 KB. Grid (12, M/64) -> 768 blocks = all-resident.
// ---------------------------------------------------------------------------
template <int KTOT>
__global__ __launch_bounds__(256, 3) void gemm_m97_64_relu_f16(
    const _Float16* __restrict__ A, const _Float16* __restrict__ Bw,
    const float* __restrict__ bias, _Float16* __restrict__ out, int N) {
  __shared__ __align__(16) _Float16 As[2][64 * 32];
  __shared__ __align__(16) _Float16 Bs[2][128 * 32];

  const int t = threadIdx.x;
  const int lane = t & 63;
  const int wave = t >> 6;
  const int wm = wave >> 1, wn = wave & 1;
  const int bcol = blockIdx.x * 128;
  const int brow = blockIdx.y * 64;

  const int scol = ((t & 3) ^ ((t >> 3) & 3)) * 8;
  const _Float16* Ab = A + (size_t)(brow + (t >> 2)) * KTOT + scol;
  const _Float16* Bb = Bw + (size_t)(bcol + (t >> 2)) * KTOT + scol;

  f32x4 acc[2][4] = {};

  for (int kt = 0; kt < KTOT / 64; ++kt) {
    __syncthreads();
#pragma unroll
    for (int kk = 0; kk < 2; ++kk) {
      gload_lds16(Ab + kt * 64 + kk * 32, &As[kk][t * 8]);   // 64 rows (t<256 covers half; rows via t>>2)
      gload_lds16(Bb + kt * 64 + kk * 32, &Bs[kk][t * 8]);
      gload_lds16(Bb + (size_t)64 * KTOT + kt * 64 + kk * 32, &Bs[kk][2048 + t * 8]);
    }
    asm volatile("s_waitcnt vmcnt(0)" ::: "memory");
    __syncthreads();
#pragma unroll
    for (int kk = 0; kk < 2; ++kk) {
      h8 af[2], bf[4];
#pragma unroll
      for (int m = 0; m < 2; ++m) {
        const int row = wm * 32 + m * 16 + (lane & 15);
        af[m] = *(const h8*)&As[kk][row * 32 + ((lane >> 4) ^ ((row >> 1) & 3)) * 8];
      }
#pragma unroll
      for (int n = 0; n < 4; ++n) {
        const int row = wn * 64 + n * 16 + (lane & 15);
        bf[n] = *(const h8*)&Bs[kk][row * 32 + ((lane >> 4) ^ ((row >> 1) & 3)) * 8];
      }
#pragma unroll
      for (int m = 0; m < 2; ++m)
#pragma unroll
        for (int n = 0; n < 4; ++n)
          acc[m][n] = __builtin_amdgcn_mfma_f32_16x16x32_f16(af[m], bf[n], acc[m][n], 0, 0, 0);
    }
  }

#pragma unroll
  for (int m = 0; m < 2; ++m)
#pragma unroll
    for (int n = 0; n < 4; ++n) {
      const int col = bcol + wn * 64 + n * 16 + (lane & 15);
      const float bb = bias[col];
#pragma unroll
      for (int r = 0; r < 4; ++r) {
        const int row = brow + wm * 32 + m * 16 + (lane >> 4) * 4 + r;
        float val = acc[m][n][r] + bb;
        out[(size_t)row * N + col] = (_Float16)(val > 0.f ? val : 0.f);
      }
    }
}

// ---------------------------------------------------------------------------
// Bilinear (round-5 exact): out[b,h,v,q] = sum_k vh*(h16*qh) + hbias[h]
// ---------------------------------------------------------------------------
__global__ __launch_bounds__(256, 3) void bilinear_m97_f16(
    const _Float16* __restrict__ vh, const _Float16* __restrict__ qh,
    const _Float16* __restrict__ h16, const float* __restrict__ hbias,
    float* __restrict__ out) {
  __shared__ __align__(16) _Float16 As[2][128 * 32];
  __shared__ __align__(16) _Float16 Bs[2][128 * 32];
  __shared__ __align__(16) _Float16 hl[HK_];

  const int t = threadIdx.x;
  const int lane = t & 63;
  const int wave = t >> 6;
  const int wm = wave >> 1, wn = wave & 1;
  const int mt = blockIdx.x;
  const int bh = blockIdx.y;
  const int b = bh >> 3, h = bh & 7;

  const int scol = ((t & 3) ^ ((t >> 3) & 3)) * 8;
  const _Float16* Ab = vh + ((size_t)b * NV_ + mt * 128 + (t >> 2)) * HK_ + scol;
  const _Float16* Qb = qh + (size_t)b * NQ_ * HK_;

  for (int i = t; i < HK_ / 8; i += 256)
    *(h8*)&hl[i * 8] = *(const h8*)&h16[(size_t)h * HK_ + i * 8];

  const int qrow = t >> 2;
  const int qs = t & 3;

  f32x4 acc[4][4] = {};

  for (int kt = 0; kt < HK_ / 64; ++kt) {
    __syncthreads();
#pragma unroll
    for (int kk = 0; kk < 2; ++kk) {
      gload_lds16(Ab + kt * 64 + kk * 32, &As[kk][t * 8]);
      gload_lds16(Ab + (size_t)64 * HK_ + kt * 64 + kk * 32, &As[kk][2048 + t * 8]);
    }
#pragma unroll
    for (int u = 0; u < 2; ++u) {
      const int row = u * 64 + qrow;
#pragma unroll
      for (int kk = 0; kk < 2; ++kk) {
        const int col = kt * 64 + kk * 32 + qs * 8;
        h8 qv = *(const h8*)&Qb[(size_t)row * HK_ + col];
        h8 hv = *(const h8*)&hl[col];
        *(h8*)&Bs[kk][row * 32 + (qs ^ ((row >> 1) & 3)) * 8] = qv * hv;
      }
    }
    asm volatile("s_waitcnt vmcnt(0)" ::: "memory");
    __syncthreads();
#pragma unroll
    for (int kk = 0; kk < 2; ++kk) {
      h8 af[4], bf[4];
#pragma unroll
      for (int m = 0; m < 4; ++m) {
        const int row = wm * 64 + m * 16 + (lane & 15);
        af[m] = *(const h8*)&As[kk][row * 32 + ((lane >> 4) ^ ((row >> 1) & 3)) * 8];
      }
#pragma unroll
      for (int n = 0; n < 4; ++n) {
        const int row = wn * 64 + n * 16 + (lane & 15);
        bf[n] = *(const h8*)&Bs[kk][row * 32 + ((lane >> 4) ^ ((row >> 1) & 3)) * 8];
      }
#pragma unroll
      for (int m = 0; m < 4; ++m)
#pragma unroll
        for (int n = 0; n < 4; ++n)
          acc[m][n] = __builtin_amdgcn_mfma_f32_16x16x32_f16(af[m], bf[n], acc[m][n], 0, 0, 0);
    }
  }

  const float bb = hbias[h];
  float* O = out + ((size_t)bh * NV_ + (size_t)mt * 128) * NQ_;
#pragma unroll
  for (int m = 0; m < 4; ++m)
#pragma unroll
    for (int n = 0; n < 4; ++n)
#pragma unroll
      for (int r = 0; r < 4; ++r) {
        const int row = wm * 64 + m * 16 + (lane >> 4) * 4 + r;
        const int col = wn * 64 + n * 16 + (lane & 15);
        O[(size_t)row * NQ_ + col] = acc[m][n][r] + bb;
      }
}

// ---------------------------------------------------------------------------
// Workspace layout (bytes): v16@0 (67,108,864) q16@67108864 (8,388,608)
// Wv16@75497472 (6,291,456) Wq16@81788928 (3,145,728) vh@84934656 (50,331,648)
// qh@135266304 (12,582,912) h16@147849216 (24,576) total 147,873,792
// ---------------------------------------------------------------------------
extern "C" void kernel_launch(void* const* d_in, const int* in_sizes, int n_in,
                              void* d_out, int out_size, void* d_ws,
                              size_t ws_size, hipStream_t stream) {
  const float* v = (const float*)d_in[0];
  const float* q = (const float*)d_in[1];
  const float* Wv = (const float*)d_in[2];
  const float* bv = (const float*)d_in[3];
  const float* Wq = (const float*)d_in[4];
  const float* bq = (const float*)d_in[5];
  const float* hmat = (const float*)d_in[6];
  const float* hbias = (const float*)d_in[7];

  if (ws_size < 147873792u) return;

  char* ws = (char*)d_ws;
  _Float16* v16 = (_Float16*)(ws);
  _Float16* q16 = (_Float16*)(ws + 67108864);
  _Float16* Wv16 = (_Float16*)(ws + 75497472);
  _Float16* Wq16 = (_Float16*)(ws + 81788928);
  _Float16* vh = (_Float16*)(ws + 84934656);
  _Float16* qh = (_Float16*)(ws + 135266304);
  _Float16* h16 = (_Float16*)(ws + 147849216);

  cvt_all<<<dim3(20742), 256, 0, stream>>>(v, q, Wv, Wq, hmat,
                                           v16, q16, Wv16, Wq16, h16);

  // v_ = relu(v @ Wv^T + bv): grid (12,128) = 1536 blocks, chunked XCD remap
  gemm_m97_relu_f16<VD_, true><<<dim3(HK_ / 128, 16384 / 128), 256, 0, stream>>>(
      v16, Wv16, bv, vh, HK_);
  // q_ = relu(q @ Wq^T + bq): BM=64 -> grid (12,64) = 768 blocks all-resident
  gemm_m97_64_relu_f16<QD_><<<dim3(HK_ / 128, 4096 / 64), 256, 0, stream>>>(
      q16, Wq16, bq, qh, HK_);

  // logits: grid (4, 256) = 1024 blocks
  bilinear_m97_f16<<<dim3(NV_ / 128, B_ * HO_), 256, 0, stream>>>(
      vh, qh, h16, hbias, (float*)d_out);
}